// Round 6
// baseline (1558.615 us; speedup 1.0000x reference)
//
#include <hip/hip_runtime.h>
#include <stdint.h>

#define DEV __device__ __forceinline__

typedef __bf16 bf16x8 __attribute__((ext_vector_type(8)));
typedef float  f32x4  __attribute__((ext_vector_type(4)));

struct alignas(8) U16x4 { uint16_t x, y, z, w; };

DEV uint16_t f2bf(float f) {
  union { float f; uint32_t u; } v; v.f = f;
  uint32_t r = v.u + 0x7fffu + ((v.u >> 16) & 1u);
  return (uint16_t)(r >> 16);
}

DEV void gload16(const void* g, void* l) {
  __builtin_amdgcn_global_load_lds((__attribute__((address_space(1))) void*)(g),
                                   (__attribute__((address_space(3))) void*)(l),
                                   16, 0, 0);
}

// ---------------------------------------------------------------------------
// Weight transpose + f32->bf16:  in [R][C] f32  ->  out [C][R] bf16
// ---------------------------------------------------------------------------
__global__ __launch_bounds__(1024) void transpose_cvt(
    const float* __restrict__ in, uint16_t* __restrict__ out, int R, int C) {
  __shared__ float tile[32][33];
  const int tx = threadIdx.x, ty = threadIdx.y;
  const int r = blockIdx.y * 32 + ty, c = blockIdx.x * 32 + tx;
  tile[ty][tx] = in[(size_t)r * C + c];
  __syncthreads();
  const int oc = blockIdx.x * 32 + ty;   // output row (former column)
  const int orr = blockIdx.y * 32 + tx;  // output col (former row)
  out[(size_t)oc * R + orr] = f2bf(tile[tx][ty]);
}

// ---------------------------------------------------------------------------
// Slice src into modal1/modal2 token-major bf16 [16384][1024]
// ---------------------------------------------------------------------------
__global__ __launch_bounds__(256) void cvt_modal(
    const float* __restrict__ src, uint16_t* __restrict__ m1, uint16_t* __restrict__ m2) {
  const int idx = blockIdx.x * 256 + threadIdx.x;  // float4 group
  const int E = idx * 4;
  const int t = E >> 10, dd = E & 1023;
  const size_t s1 = ((size_t)(t >> 7) * 256 + (t & 127)) * 1024 + dd;
  float4 a = *(const float4*)&src[s1];
  float4 b = *(const float4*)&src[s1 + 131072];  // s + 128 rows
  U16x4 pa{f2bf(a.x), f2bf(a.y), f2bf(a.z), f2bf(a.w)};
  U16x4 pb{f2bf(b.x), f2bf(b.y), f2bf(b.z), f2bf(b.w)};
  *(U16x4*)&m1[E] = pa;
  *(U16x4*)&m2[E] = pb;
}

// ---------------------------------------------------------------------------
// GEMM, m201-style 8-phase schedule. 256x256 tile, BK=64, 8 waves (2Mx4N,
// 128x64 per wave), 2-dbuf LDS (128 KiB), per K-tile 4 phases:
//   {ds-read quadrant frags | stage granule of t+2 -> barrier -> lgkm(0)
//    -> setprio(1) 16 MFMA setprio(0) -> barrier}, vmcnt(8) once per tile.
// LDS layout: A[dbuf][256][64] elems at 0 / 16384; B same at 32768.
// XOR swizzle: element (row, chunk8) stored at chunk^(row&7) (involution);
// staging fetches inverse-swizzled global src, linear LDS dest.
// Staging hazards audited: A rows {0-63,128-191}(t) read at P1 -> staged P2;
// B fully read by P2 -> staged P3; A rows {64-127,192-255} read P3 -> P4.
// C[M][N] = A[M][K] @ Bt[N][K]^T + bias (+relu) (+resid)
// RESID: 0 none, 1 plain f32 [M][1024], 2 strided src slice (soff)
// Requires M%256==0, N%256==0, K%64==0, K>=128, grid%8==0.
// ---------------------------------------------------------------------------
#define RD_A(QA)                                                              \
  _Pragma("unroll") for (int f = 0; f < 4; ++f)                               \
    _Pragma("unroll") for (int ks = 0; ks < 2; ++ks)                          \
      afr[f][ks] = *(const bf16x8*)&lds[abuf + aBase + (QA)*4096 + f*1024 +   \
                                        (c0 ^ (ks << 5))];

#define RD_B(QB, BFR)                                                         \
  _Pragma("unroll") for (int n = 0; n < 2; ++n)                               \
    _Pragma("unroll") for (int ks = 0; ks < 2; ++ks)                          \
      BFR[n][ks] = *(const bf16x8*)&lds[bbuf + bBase + (QB)*2048 + n*1024 +   \
                                        (c0 ^ (ks << 5))];

#define PH(QA, QB, BFR, READS, STAGES, ENDW)                                  \
  {                                                                           \
    READS                                                                     \
    STAGES                                                                    \
    __builtin_amdgcn_s_barrier();                                             \
    asm volatile("s_waitcnt lgkmcnt(0)" ::: "memory");                        \
    __builtin_amdgcn_sched_barrier(0);                                        \
    __builtin_amdgcn_s_setprio(1);                                            \
    _Pragma("unroll") for (int f = 0; f < 4; ++f)                             \
      _Pragma("unroll") for (int n = 0; n < 2; ++n)                           \
        _Pragma("unroll") for (int ks = 0; ks < 2; ++ks)                      \
          acc[(QA)*4 + f][(QB)*2 + n] =                                       \
              __builtin_amdgcn_mfma_f32_16x16x32_bf16(                        \
                  afr[f][ks], BFR[n][ks], acc[(QA)*4 + f][(QB)*2 + n], 0, 0, 0); \
    __builtin_amdgcn_s_setprio(0);                                            \
    __builtin_amdgcn_sched_barrier(0);                                        \
    ENDW                                                                      \
    __builtin_amdgcn_s_barrier();                                             \
    __builtin_amdgcn_sched_barrier(0);                                        \
  }

#define TILE8(T, ST, ENDW)                                                    \
  {                                                                           \
    const int abuf = ((T) & 1) * 16384;                                       \
    const int bbuf = 32768 + abuf;                                            \
    const int koff = ((T) + 2) << 6;                                          \
    PH(0, 0, bfr0, { RD_A(0) RD_B(0, bfr0) }, {}, {})                         \
    PH(0, 1, bfr1, { RD_B(1, bfr1) },                                         \
       { if (ST) {                                                            \
           gload16(gA + koff, &lds[abuf + wS]);                               \
           gload16(gA + kR2 + koff, &lds[abuf + 8192 + wS]);                  \
         } }, {})                                                             \
    PH(1, 0, bfr0, { RD_A(1) },                                               \
       { if (ST) {                                                            \
           gload16(gB + koff, &lds[bbuf + wS]);                               \
           gload16(gB + kR1 + koff, &lds[bbuf + 4096 + wS]);                  \
           gload16(gB + kR2 + koff, &lds[bbuf + 8192 + wS]);                  \
           gload16(gB + kR3 + koff, &lds[bbuf + 12288 + wS]);                 \
         } }, {})                                                             \
    PH(1, 1, bfr1, {},                                                        \
       { if (ST) {                                                            \
           gload16(gA + kR1 + koff, &lds[abuf + 4096 + wS]);                  \
           gload16(gA + kR3 + koff, &lds[abuf + 12288 + wS]);                 \
         } }, ENDW)                                                           \
  }

template <int RESID, bool RELU, bool OUTF32>
__global__ __launch_bounds__(512, 2) void gemm8p(
    const uint16_t* __restrict__ A, const uint16_t* __restrict__ Bt,
    const float* __restrict__ bias, const float* __restrict__ resid,
    void* __restrict__ outp, int N, int K, int nbn, int soff) {
  __shared__ __align__(16) uint16_t lds[65536];  // 128 KiB

  // ---- block swizzle: XCD-contiguous, bm-major decode ----
  const int nwg = gridDim.x;
  const int sw = (blockIdx.x & 7) * (nwg >> 3) + (blockIdx.x >> 3);
  const int bm = sw / nbn, bn = sw % nbn;
  const int brow = bm << 8, bcol = bn << 8;

  const int tid = threadIdx.x;
  const int w = tid >> 6, lane = tid & 63;
  const int l15 = lane & 15, lhi = lane >> 4, l7 = lane & 7, l3 = lane >> 3;
  const int wm = w >> 2, wn = w & 3;  // 2M x 4N waves

  // ---- fragment-read addressing (swizzled chunk) ----
  const int c0 = ((lhi ^ l7) << 3);          // elems; kstep1 = c0 ^ 32
  const int aBase = (wm * 128 + l15) * 64;   // rows wm*128 + qa*64 + f*16 + l15
  const int bBase = (wn * 64 + l15) * 64;    // rows wn*64 + qb*32 + f*16 + l15

  // ---- staging addressing (linear LDS dest, inverse-swizzled global) ----
  const size_t Kz = (size_t)K;
  const int srcoff = ((l7 ^ l3) << 3);
  const uint16_t* gA = A + (size_t)(brow + w * 8 + l3) * Kz + srcoff;
  const uint16_t* gB = Bt + (size_t)(bcol + w * 8 + l3) * Kz + srcoff;
  const size_t kR1 = 64 * Kz, kR2 = 128 * Kz, kR3 = 192 * Kz;
  const int wS = w * 512;  // wave-uniform LDS elem base; HW adds lane*16B

  f32x4 acc[8][4];
  const f32x4 z = {0.f, 0.f, 0.f, 0.f};
#pragma unroll
  for (int m = 0; m < 8; ++m)
#pragma unroll
    for (int n = 0; n < 4; ++n) acc[m][n] = z;

  const int nt = K >> 6;

  // ---- prologue: stage tiles 0 and 1 (8 granule-loads each) ----
#pragma unroll
  for (int pt = 0; pt < 2; ++pt) {
    const int ab = pt * 16384, bb = 32768 + ab;
    const int ko = pt << 6;
    gload16(gA + ko, &lds[ab + wS]);
    gload16(gA + kR1 + ko, &lds[ab + 4096 + wS]);
    gload16(gA + kR2 + ko, &lds[ab + 8192 + wS]);
    gload16(gA + kR3 + ko, &lds[ab + 12288 + wS]);
    gload16(gB + ko, &lds[bb + wS]);
    gload16(gB + kR1 + ko, &lds[bb + 4096 + wS]);
    gload16(gB + kR2 + ko, &lds[bb + 8192 + wS]);
    gload16(gB + kR3 + ko, &lds[bb + 12288 + wS]);
  }
  asm volatile("s_waitcnt vmcnt(8)" ::: "memory");  // tile 0 landed
  __builtin_amdgcn_s_barrier();
  __builtin_amdgcn_sched_barrier(0);

  {
    bf16x8 afr[4][2], bfr0[2][2], bfr1[2][2];
    int t = 0;
    for (; t < nt - 2; ++t)
      TILE8(t, true, asm volatile("s_waitcnt vmcnt(8)" ::: "memory");)
    TILE8(t, false, asm volatile("s_waitcnt vmcnt(0)" ::: "memory");)
    ++t;
    TILE8(t, false, {})
  }

  // ---- epilogue: wave writes 128x64 at (brow+wm*128, bcol+wn*64) ----
#pragma unroll
  for (int n = 0; n < 4; ++n) {
    const int col = bcol + wn * 64 + n * 16 + l15;
    const float bs = bias[col];
#pragma unroll
    for (int m = 0; m < 8; ++m) {
#pragma unroll
      for (int r = 0; r < 4; ++r) {
        const int row = brow + wm * 128 + m * 16 + lhi * 4 + r;
        float v = acc[m][n][r] + bs;
        if (RELU) v = fmaxf(v, 0.f);
        if (RESID == 1) v += resid[(size_t)row * 1024 + col];
        if (RESID == 2)
          v += resid[((size_t)(row >> 7) * 256 + soff + (row & 127)) * 1024 + col];
        if (OUTF32)
          ((float*)outp)[(size_t)row * N + col] = v;
        else
          ((uint16_t*)outp)[(size_t)row * N + col] = f2bf(v);
      }
    }
  }
}

// ---------------------------------------------------------------------------
// Attention core: one block per (b,h). S=128, dh=64. Q,K,V bf16 [t][1024].
// ---------------------------------------------------------------------------
__global__ __launch_bounds__(256) void attn_kern(
    const uint16_t* __restrict__ Q, const uint16_t* __restrict__ Kv,
    const uint16_t* __restrict__ V, uint16_t* __restrict__ O) {
  __shared__ uint16_t sm[24576];  // 48 KB: [Q 16K | K 16K | Vt 16K]; P aliases Q+K
  uint16_t* sQ = sm;
  uint16_t* sK = sm + 8192;
  uint16_t* sVt = sm + 16384;
  uint16_t* sP = sm;  // 128x128 bf16 = 32KB, reuses Q+K after barrier
  const int bh = blockIdx.x, b = bh >> 4, h = bh & 15;
  const int tid = threadIdx.x, w = tid >> 6, lane = tid & 63, l15 = lane & 15, lhi = lane >> 4;
  const size_t base = (size_t)b * 131072 + h * 64;

  for (int i = 0; i < 4; ++i) {
    const int gidx = i * 256 + tid;
    const int row = gidx >> 3, co = (gidx & 7) * 8;
    *(uint4*)&sQ[row * 64 + co] = *(const uint4*)&Q[base + (size_t)row * 1024 + co];
    *(uint4*)&sK[row * 64 + co] = *(const uint4*)&Kv[base + (size_t)row * 1024 + co];
  }
  {
    const int r = tid >> 1, cb = (tid & 1) * 32;
    for (int jj = 0; jj < 4; ++jj) {
      uint4 vv = *(const uint4*)&V[base + (size_t)r * 1024 + cb + jj * 8];
      const uint16_t* e = (const uint16_t*)&vv;
      for (int j = 0; j < 8; ++j) sVt[(cb + jj * 8 + j) * 128 + r] = e[j];
    }
  }
  __syncthreads();

  f32x4 s[2][8];
  const f32x4 z = {0.f, 0.f, 0.f, 0.f};
  for (int m = 0; m < 2; ++m)
    for (int n = 0; n < 8; ++n) s[m][n] = z;
#pragma unroll
  for (int kk = 0; kk < 2; ++kk) {
    bf16x8 aq[2];
#pragma unroll
    for (int m = 0; m < 2; ++m)
      aq[m] = *(const bf16x8*)&sQ[(w * 32 + m * 16 + l15) * 64 + kk * 32 + lhi * 8];
#pragma unroll
    for (int n = 0; n < 8; ++n) {
      bf16x8 bk = *(const bf16x8*)&sK[(n * 16 + l15) * 64 + kk * 32 + lhi * 8];
#pragma unroll
      for (int m = 0; m < 2; ++m)
        s[m][n] = __builtin_amdgcn_mfma_f32_16x16x32_bf16(aq[m], bk, s[m][n], 0, 0, 0);
    }
  }

  for (int m = 0; m < 2; ++m) {
    float mx[4], sum[4];
#pragma unroll
    for (int r = 0; r < 4; ++r) {
      float v = s[m][0][r];
      for (int n = 1; n < 8; ++n) v = fmaxf(v, s[m][n][r]);
      for (int msk = 1; msk < 16; msk <<= 1) v = fmaxf(v, __shfl_xor(v, msk, 64));
      mx[r] = v;
      sum[r] = 0.f;
    }
    for (int n = 0; n < 8; ++n)
      for (int r = 0; r < 4; ++r) {
        float e = __expf((s[m][n][r] - mx[r]) * 0.125f);
        s[m][n][r] = e;
        sum[r] += e;
      }
#pragma unroll
    for (int r = 0; r < 4; ++r) {
      float t = sum[r];
      for (int msk = 1; msk < 16; msk <<= 1) t += __shfl_xor(t, msk, 64);
      sum[r] = 1.f / t;
    }
    for (int n = 0; n < 8; ++n)
      for (int r = 0; r < 4; ++r) s[m][n][r] *= sum[r];
  }
  __syncthreads();

  for (int m = 0; m < 2; ++m)
    for (int n = 0; n < 8; ++n)
      for (int r = 0; r < 4; ++r)
        sP[(w * 32 + m * 16 + lhi * 4 + r) * 128 + n * 16 + l15] = f2bf(s[m][n][r]);
  __syncthreads();

  f32x4 o[2][4];
  for (int m = 0; m < 2; ++m)
    for (int n = 0; n < 4; ++n) o[m][n] = z;
#pragma unroll
  for (int kk = 0; kk < 4; ++kk) {
    bf16x8 ap[2];
#pragma unroll
    for (int m = 0; m < 2; ++m)
      ap[m] = *(const bf16x8*)&sP[(w * 32 + m * 16 + l15) * 128 + kk * 32 + lhi * 8];
#pragma unroll
    for (int n = 0; n < 4; ++n) {
      bf16x8 bv = *(const bf16x8*)&sVt[(n * 16 + l15) * 128 + kk * 32 + lhi * 8];
#pragma unroll
      for (int m = 0; m < 2; ++m)
        o[m][n] = __builtin_amdgcn_mfma_f32_16x16x32_bf16(ap[m], bv, o[m][n], 0, 0, 0);
    }
  }
  for (int m = 0; m < 2; ++m)
    for (int n = 0; n < 4; ++n)
      for (int r = 0; r < 4; ++r) {
        const int q = w * 32 + m * 16 + lhi * 4 + r, c = n * 16 + l15;
        O[base + (size_t)q * 1024 + c] = f2bf(o[m][n][r]);
      }
}

// ---------------------------------------------------------------------------
// LN2D: per-batch-element layernorm over 128x1024. 512 threads.
// ---------------------------------------------------------------------------
__global__ __launch_bounds__(512) void ln2d(
    const float* __restrict__ x, const float* __restrict__ g, const float* __restrict__ bet,
    float* __restrict__ outf, int bstride, uint16_t* __restrict__ outbf) {
  const int b = blockIdx.x, tid = threadIdx.x;
  const float4* xb = (const float4*)(x + (size_t)b * 131072);
  float s = 0.f, ss = 0.f;
  for (int i = tid; i < 32768; i += 512) {
    float4 v = xb[i];
    s += (v.x + v.y) + (v.z + v.w);
    ss += (v.x * v.x + v.y * v.y) + (v.z * v.z + v.w * v.w);
  }
#pragma unroll
  for (int m = 1; m < 64; m <<= 1) {
    s += __shfl_xor(s, m, 64);
    ss += __shfl_xor(ss, m, 64);
  }
  __shared__ float red[16];
  __shared__ float stats[2];
  const int w = tid >> 6;
  if ((tid & 63) == 0) {
    red[w] = s;
    red[8 + w] = ss;
  }
  __syncthreads();
  if (tid == 0) {
    float S = 0.f, SS = 0.f;
    for (int i = 0; i < 8; ++i) { S += red[i]; SS += red[8 + i]; }
    const float mu = S * (1.f / 131072.f);
    const float var = SS * (1.f / 131072.f) - mu * mu;
    stats[0] = mu;
    stats[1] = rsqrtf(var + 1e-5f);
  }
  __syncthreads();
  const float mu = stats[0], rs = stats[1];
  float* of = outf + (size_t)b * (size_t)bstride;
  uint16_t* ob = outbf ? outbf + (size_t)b * 131072 : nullptr;
  const float4* g4 = (const float4*)g;
  const float4* b4 = (const float4*)bet;
  for (int i = tid; i < 32768; i += 512) {
    float4 v = xb[i], gg = g4[i], bb = b4[i];
    float4 o;
    o.x = (v.x - mu) * rs * gg.x + bb.x;
    o.y = (v.y - mu) * rs * gg.y + bb.y;
    o.z = (v.z - mu) * rs * gg.z + bb.z;
    o.w = (v.w - mu) * rs * gg.w + bb.w;
    *(float4*)&of[(size_t)i * 4] = o;
    if (ob) {
      U16x4 u{f2bf(o.x), f2bf(o.y), f2bf(o.z), f2bf(o.w)};
      *(U16x4*)&ob[(size_t)i * 4] = u;
    }
  }
}

// ---------------------------------------------------------------------------
extern "C" void kernel_launch(void* const* d_in, const int* in_sizes, int n_in,
                              void* d_out, int out_size, void* d_ws, size_t ws_size,
                              hipStream_t stream) {
  const float* src = (const float*)d_in[0];
  const float* Wq = (const float*)d_in[1];
  const float* bq = (const float*)d_in[2];
  const float* Wk = (const float*)d_in[3];
  const float* bk = (const float*)d_in[4];
  const float* Wv = (const float*)d_in[5];
  const float* bv = (const float*)d_in[6];
  const float* Wo = (const float*)d_in[7];
  const float* bo = (const float*)d_in[8];
  const float* W1 = (const float*)d_in[9];
  const float* b1 = (const float*)d_in[10];
  const float* W2 = (const float*)d_in[11];
  const float* b2 = (const float*)d_in[12];
  const float* g1 = (const float*)d_in[13];
  const float* be1 = (const float*)d_in[14];
  const float* g2 = (const float*)d_in[15];
  const float* be2 = (const float*)d_in[16];
  float* dout = (float*)d_out;
  char* ws = (char*)d_ws;

  const size_t MB = 1024 * 1024;
  uint16_t* wq_t = (uint16_t*)(ws + 0 * MB);
  uint16_t* wk_t = (uint16_t*)(ws + 2 * MB);
  uint16_t* wv_t = (uint16_t*)(ws + 4 * MB);
  uint16_t* wo_t = (uint16_t*)(ws + 6 * MB);
  uint16_t* w1_t = (uint16_t*)(ws + 8 * MB);   // [4096][1024]
  uint16_t* w2_t = (uint16_t*)(ws + 16 * MB);  // [1024][4096]
  uint16_t* m1bf = (uint16_t*)(ws + 24 * MB);  // final m1 bf16 (phase-B KV src)
  uint16_t* mod2 = (uint16_t*)(ws + 56 * MB);
  uint16_t* QB = (uint16_t*)(ws + 88 * MB);
  uint16_t* KB = (uint16_t*)(ws + 120 * MB);
  uint16_t* VB = (uint16_t*)(ws + 152 * MB);
  uint16_t* ATT = (uint16_t*)(ws + 184 * MB);
  uint16_t* Hbf = QB;  // 128 MB FFN hidden aliases QB..ATT (dead by then)
  uint16_t* mod1 = (uint16_t*)(ws + 216 * MB);
  float* XA = (float*)(ws + 248 * MB);
  float* YF = (float*)(ws + 312 * MB);
  uint16_t* YBF = (uint16_t*)(ws + 376 * MB);
  // total: 408 MB

  dim3 tb(32, 32);
  transpose_cvt<<<dim3(32, 32), tb, 0, stream>>>(Wq, wq_t, 1024, 1024);
  transpose_cvt<<<dim3(32, 32), tb, 0, stream>>>(Wk, wk_t, 1024, 1024);
  transpose_cvt<<<dim3(32, 32), tb, 0, stream>>>(Wv, wv_t, 1024, 1024);
  transpose_cvt<<<dim3(32, 32), tb, 0, stream>>>(Wo, wo_t, 1024, 1024);
  transpose_cvt<<<dim3(128, 32), tb, 0, stream>>>(W1, w1_t, 1024, 4096);
  transpose_cvt<<<dim3(32, 128), tb, 0, stream>>>(W2, w2_t, 4096, 1024);
  cvt_modal<<<16384, 256, 0, stream>>>(src, mod1, mod2);

  auto phase = [&](const uint16_t* qsrc, const uint16_t* kvsrc, int soff,
                   float* out_f, uint16_t* out_bf) {
    // projections: M=16384, N=1024, K=1024 -> 256 blocks, nbn=4
    gemm8p<0, false, false><<<256, 512, 0, stream>>>(qsrc, wq_t, bq, nullptr, QB,
                                                     1024, 1024, 4, 0);
    gemm8p<0, false, false><<<256, 512, 0, stream>>>(kvsrc, wk_t, bk, nullptr, KB,
                                                     1024, 1024, 4, 0);
    gemm8p<0, false, false><<<256, 512, 0, stream>>>(kvsrc, wv_t, bv, nullptr, VB,
                                                     1024, 1024, 4, 0);
    attn_kern<<<2048, 256, 0, stream>>>(QB, KB, VB, ATT);
    // out-proj + residual from src slice
    gemm8p<2, false, true><<<256, 512, 0, stream>>>(ATT, wo_t, bo, src, XA,
                                                    1024, 1024, 4, soff);
    ln2d<<<128, 512, 0, stream>>>(XA, g1, be1, YF, 131072, YBF);
    // FFN: 16384x4096x1024 (nbn=16) then 16384x1024x4096 (nbn=4)
    gemm8p<0, true, false><<<1024, 512, 0, stream>>>(YBF, w1_t, b1, nullptr, Hbf,
                                                     4096, 1024, 16, 0);
    gemm8p<1, false, true><<<256, 512, 0, stream>>>(Hbf, w2_t, b2, YF, XA,
                                                    1024, 4096, 4, 0);
    ln2d<<<128, 512, 0, stream>>>(XA, g2, be2, out_f, 262144, out_bf);
  };

  phase(mod1, mod2, 0, dout, m1bf);
  phase(mod2, m1bf, 128, dout + 131072, nullptr);

  (void)in_sizes; (void)n_in; (void)out_size; (void)ws_size;
}